// Round 1
// baseline (212.555 us; speedup 1.0000x reference)
//
#include <hip/hip_runtime.h>
#include <hip/hip_bf16.h>
#include <math.h>

#define NB 16
#define NS 512
#define ND 2048

typedef __attribute__((ext_vector_type(4))) float  f32x4v;
typedef __attribute__((ext_vector_type(8))) short  short8v;
typedef __attribute__((ext_vector_type(4))) float  accv;

__device__ __forceinline__ unsigned short f2bf(float f) {
  union { float f; unsigned u; } v; v.f = f;
  unsigned r = v.u + 0x7FFFu + ((v.u >> 16) & 1u);   // RNE
  return (unsigned short)(r >> 16);
}

// ---------------- K1: per-row mean / rstd ----------------
__global__ __launch_bounds__(256) void k_meanvar(const float* __restrict__ x,
                                                 float* __restrict__ mv) {
  int row = blockIdx.x;                       // 0..B*S-1
  const float* xr = x + (size_t)row * ND;
  int tid = threadIdx.x;
  float s = 0.f, ss = 0.f;
#pragma unroll
  for (int i = 0; i < 2; ++i) {
    f32x4v v = *reinterpret_cast<const f32x4v*>(xr + tid * 8 + i * 4);
#pragma unroll
    for (int j = 0; j < 4; ++j) { s += v[j]; ss += v[j] * v[j]; }
  }
#pragma unroll
  for (int off = 32; off > 0; off >>= 1) {
    s  += __shfl_down(s, off);
    ss += __shfl_down(ss, off);
  }
  __shared__ float red[8];
  int wid = tid >> 6, lane = tid & 63;
  if (lane == 0) { red[wid * 2] = s; red[wid * 2 + 1] = ss; }
  __syncthreads();
  if (tid == 0) {
    float S1 = red[0] + red[2] + red[4] + red[6];
    float S2 = red[1] + red[3] + red[5] + red[7];
    float mean = S1 * (1.0f / ND);
    float var  = S2 * (1.0f / ND) - mean * mean;
    mv[2 * row]     = mean;
    mv[2 * row + 1] = rsqrtf(var + 1e-5f);
  }
}

// ---------------- K2: normalize + transpose -> yT[b][d][t] (bf16) ----------------
// LDS: 64t x 64d bf16 tile, XOR swizzle at 4B granularity:
//   element (t,d) -> word  t*32 + ((d>>1) ^ (t&31)),  halfword d&1
__global__ __launch_bounds__(256) void k_normT(const float* __restrict__ x,
                                               const float* __restrict__ mv,
                                               const float* __restrict__ gamma,
                                               const float* __restrict__ beta,
                                               unsigned short* __restrict__ yT) {
  int d0 = blockIdx.x * 64, t0 = blockIdx.y * 64, bb = blockIdx.z;
  __shared__ unsigned int lds[64 * 32];
  int tid = threadIdx.x;
  {
    int tl = tid >> 2;          // local t 0..63
    int c  = tid & 3;           // 16-wide d chunk
    int trow = bb * NS + t0 + tl;
    float mean = mv[2 * trow], rstd = mv[2 * trow + 1];
    const float* xr = x + (size_t)trow * ND + d0;
    int k = tl & 31;
#pragma unroll
    for (int q = 0; q < 4; ++q) {
      int dl = c * 16 + q * 4;
      f32x4v v = *reinterpret_cast<const f32x4v*>(xr + dl);
      f32x4v g = *reinterpret_cast<const f32x4v*>(gamma + d0 + dl);
      f32x4v b = *reinterpret_cast<const f32x4v*>(beta + d0 + dl);
      unsigned short h[4];
#pragma unroll
      for (int j = 0; j < 4; ++j) h[j] = f2bf((v[j] - mean) * rstd * g[j] + b[j]);
      lds[tl * 32 + (((dl >> 1)    ) ^ k)] = (unsigned)h[0] | ((unsigned)h[1] << 16);
      lds[tl * 32 + (((dl >> 1) + 1) ^ k)] = (unsigned)h[2] | ((unsigned)h[3] << 16);
    }
  }
  __syncthreads();
  {
    int dl = tid >> 2;          // local d 0..63
    int tc = (tid & 3) * 16;    // t chunk base
    short8v o0, o1;
#pragma unroll
    for (int i = 0; i < 16; ++i) {
      int t = tc + i;
      unsigned w = lds[t * 32 + ((dl >> 1) ^ (t & 31))];
      unsigned short val = (dl & 1) ? (unsigned short)(w >> 16)
                                    : (unsigned short)(w & 0xffffu);
      if (i < 8) o0[i] = (short)val; else o1[i - 8] = (short)val;
    }
    size_t base = ((size_t)bb * ND + d0 + dl) * NS + t0 + tc;
    *reinterpret_cast<short8v*>(yT + base)     = o0;
    *reinterpret_cast<short8v*>(yT + base + 8) = o1;
  }
}

// ---------------- K3: out = gelu(W_e @ y + bias_e) + x ----------------
// BM=128 BN=128 BK=32, 4 waves (2x2), each wave 64x64 = 4x4 mfma_f32_16x16x32_bf16
#define APITCH 40
__global__ __launch_bounds__(256) void k_gemm(const unsigned short* __restrict__ yT,
                                              const float* __restrict__ W,
                                              const float* __restrict__ bias,
                                              const float* __restrict__ x,
                                              float* __restrict__ out) {
  int n0 = blockIdx.x * 128, m0 = blockIdx.y * 128, bb = blockIdx.z;
  int e = bb < 3 ? bb : 3;
  const float* Wp          = W  + (size_t)e  * NS * NS;
  const unsigned short* Bp = yT + (size_t)bb * ND * NS;
  __shared__ unsigned short Alds[128 * APITCH];
  __shared__ unsigned short Blds[128 * APITCH];
  int tid = threadIdx.x;
  int lane = tid & 63, wid = tid >> 6;
  int wr = wid >> 1, wc = wid & 1;
  accv acc[4][4] = {};

  int lr = lane & 15, lk = (lane >> 4) * 8;

  for (int k0 = 0; k0 < NS; k0 += 32) {
    // stage A: W_e tile [m0..m0+127][k0..k0+31], fp32 -> bf16
    {
      int colq  = (tid & 7) * 4;
      int rbase = tid >> 3;             // 0..31
#pragma unroll
      for (int p = 0; p < 4; ++p) {
        int r = rbase + p * 32;
        f32x4v v = *reinterpret_cast<const f32x4v*>(Wp + (size_t)(m0 + r) * NS + k0 + colq);
        unsigned lo = (unsigned)f2bf(v[0]) | ((unsigned)f2bf(v[1]) << 16);
        unsigned hi = (unsigned)f2bf(v[2]) | ((unsigned)f2bf(v[3]) << 16);
        uint2 pk; pk.x = lo; pk.y = hi;
        *reinterpret_cast<uint2*>(&Alds[r * APITCH + colq]) = pk;
      }
    }
    // stage B: yT tile [n0..n0+127][k0..k0+31] (already k-contiguous)
    {
      int co    = (tid & 3) * 8;
      int rbase = tid >> 2;             // 0..63
#pragma unroll
      for (int p = 0; p < 2; ++p) {
        int r = rbase + p * 64;
        short8v v = *reinterpret_cast<const short8v*>(Bp + (size_t)(n0 + r) * NS + k0 + co);
        *reinterpret_cast<short8v*>(&Blds[r * APITCH + co]) = v;
      }
    }
    __syncthreads();

    short8v a[4], b[4];
#pragma unroll
    for (int mi = 0; mi < 4; ++mi)
      a[mi] = *reinterpret_cast<const short8v*>(&Alds[(wr * 64 + mi * 16 + lr) * APITCH + lk]);
#pragma unroll
    for (int ni = 0; ni < 4; ++ni)
      b[ni] = *reinterpret_cast<const short8v*>(&Blds[(wc * 64 + ni * 16 + lr) * APITCH + lk]);
#pragma unroll
    for (int mi = 0; mi < 4; ++mi)
#pragma unroll
      for (int ni = 0; ni < 4; ++ni)
        acc[mi][ni] = __builtin_amdgcn_mfma_f32_16x16x32_bf16(a[mi], b[ni], acc[mi][ni], 0, 0, 0);
    __syncthreads();
  }

  // epilogue: gelu(acc + bias_e[s]) + x
  const float* bp = bias + (size_t)e * NS;
#pragma unroll
  for (int mi = 0; mi < 4; ++mi) {
#pragma unroll
    for (int ni = 0; ni < 4; ++ni) {
#pragma unroll
      for (int r = 0; r < 4; ++r) {
        int s = m0 + wr * 64 + mi * 16 + ((lane >> 4) * 4) + r;
        int d = n0 + wc * 64 + ni * 16 + (lane & 15);
        float v = acc[mi][ni][r] + bp[s];
        float g = 0.5f * v * (1.0f + erff(v * 0.70710678118f));
        size_t idx = ((size_t)bb * NS + s) * ND + d;
        out[idx] = g + x[idx];
      }
    }
  }
}

extern "C" void kernel_launch(void* const* d_in, const int* in_sizes, int n_in,
                              void* d_out, int out_size, void* d_ws, size_t ws_size,
                              hipStream_t stream) {
  const float* x     = (const float*)d_in[0];
  const float* gamma = (const float*)d_in[1];
  const float* beta  = (const float*)d_in[2];
  // d_in[3] = Wc, d_in[4] = bc : router is dead code in the reference (unused output)
  const float* W     = (const float*)d_in[5];
  const float* bias  = (const float*)d_in[6];
  float* out = (float*)d_out;

  unsigned short* yT = (unsigned short*)d_ws;                       // B*D*S bf16 = 32 MB
  float* mv = (float*)((char*)d_ws + (size_t)NB * ND * NS * 2);     // B*S * {mean,rstd}

  k_meanvar<<<NB * NS, 256, 0, stream>>>(x, mv);
  k_normT<<<dim3(ND / 64, NS / 64, NB), 256, 0, stream>>>(x, mv, gamma, beta, yT);
  k_gemm<<<dim3(ND / 128, NS / 128, NB), 256, 0, stream>>>(yT, W, bias, x, out);
}

// Round 2
// 176.985 us; speedup vs baseline: 1.2010x; 1.2010x over previous
//
#include <hip/hip_runtime.h>
#include <hip/hip_bf16.h>
#include <math.h>

#define NB 16
#define NS 512
#define ND 2048

typedef __attribute__((ext_vector_type(4))) float  f32x4v;
typedef __attribute__((ext_vector_type(8))) short  short8v;
typedef __attribute__((ext_vector_type(4))) float  accv;

__device__ __forceinline__ unsigned short f2bf(float f) {
  union { float f; unsigned u; } v; v.f = f;
  unsigned r = v.u + 0x7FFFu + ((v.u >> 16) & 1u);   // RNE
  return (unsigned short)(r >> 16);
}

// swizzled 16B-unit index within an 8KB tile image (128 rows x 4 k-quads)
__device__ __forceinline__ int swz(int r, int kq) { return r * 4 + (kq ^ ((r >> 1) & 3)); }

#define GLL16(gp, lp) __builtin_amdgcn_global_load_lds(                        \
    (const __attribute__((address_space(1))) void*)(gp),                       \
    (__attribute__((address_space(3))) void*)(lp), 16, 0, 0)

// ---------------- K1: per-row mean / rstd (wave per row) ----------------
__global__ __launch_bounds__(256) void k_meanvar(const float* __restrict__ x,
                                                 float* __restrict__ mv) {
  int row  = blockIdx.x * 4 + (threadIdx.x >> 6);
  int lane = threadIdx.x & 63;
  const float* xr = x + (size_t)row * ND;
  float s = 0.f, ss = 0.f;
#pragma unroll
  for (int q = 0; q < 8; ++q) {
    f32x4v v = *reinterpret_cast<const f32x4v*>(xr + q * 256 + lane * 4);
#pragma unroll
    for (int j = 0; j < 4; ++j) { s += v[j]; ss += v[j] * v[j]; }
  }
#pragma unroll
  for (int off = 1; off < 64; off <<= 1) {
    s  += __shfl_xor(s, off);
    ss += __shfl_xor(ss, off);
  }
  if (lane == 0) {
    float mean = s * (1.0f / ND);
    float var  = ss * (1.0f / ND) - mean * mean;
    mv[2 * row]     = mean;
    mv[2 * row + 1] = rsqrtf(var + 1e-5f);
  }
}

// ---------------- K2: W fp32 -> bf16 tile images ----------------
// image layout: [e][mp][ks] -> 512 x 16B units; unit swz(r,kq) holds W[e][mp*128+r][ks*32+kq*8 .. +7]
__global__ __launch_bounds__(256) void k_wcvt(const float* __restrict__ W,
                                              unsigned short* __restrict__ Aimg) {
  int ks = blockIdx.x, mp = blockIdx.y, e = blockIdx.z;
  size_t img = ((size_t)(e * 4 + mp) * 16 + ks) * 4096;   // ushort units
  int tid = threadIdx.x;
#pragma unroll
  for (int u = 0; u < 2; ++u) {
    int p = u * 256 + tid;
    int r = p >> 2, cc = p & 3;
    int kq = cc ^ ((r >> 1) & 3);
    const float* src = W + ((size_t)e * NS + mp * 128 + r) * NS + ks * 32 + kq * 8;
    f32x4v v0 = *reinterpret_cast<const f32x4v*>(src);
    f32x4v v1 = *reinterpret_cast<const f32x4v*>(src + 4);
    short8v o;
#pragma unroll
    for (int j = 0; j < 4; ++j) { o[j] = (short)f2bf(v0[j]); o[4 + j] = (short)f2bf(v1[j]); }
    *reinterpret_cast<short8v*>(Aimg + img + (size_t)p * 8) = o;
  }
}

// ---------------- K3: normalize + transpose -> y tile images (bf16) ----------------
// B image layout: [b][np][ks] -> 512 x 16B units; unit swz(r,kq) holds y[b][ks*32+kq*8 .. +7][np*128+r]
__global__ __launch_bounds__(256) void k_normT(const float* __restrict__ x,
                                               const float* __restrict__ mv,
                                               const float* __restrict__ gamma,
                                               const float* __restrict__ beta,
                                               unsigned short* __restrict__ Bimg) {
  int d0 = blockIdx.x * 64, t0 = blockIdx.y * 64, bb = blockIdx.z;
  __shared__ unsigned int lds[64 * 32];
  int tid = threadIdx.x;
  {
    int tl = tid >> 2;          // local t 0..63
    int c  = tid & 3;           // 16-wide d chunk
    int trow = bb * NS + t0 + tl;
    float mean = mv[2 * trow], rstd = mv[2 * trow + 1];
    const float* xr = x + (size_t)trow * ND + d0;
    int k = tl & 31;
#pragma unroll
    for (int q = 0; q < 4; ++q) {
      int dl = c * 16 + q * 4;
      f32x4v v = *reinterpret_cast<const f32x4v*>(xr + dl);
      f32x4v g = *reinterpret_cast<const f32x4v*>(gamma + d0 + dl);
      f32x4v b = *reinterpret_cast<const f32x4v*>(beta + d0 + dl);
      unsigned short h[4];
#pragma unroll
      for (int j = 0; j < 4; ++j) h[j] = f2bf((v[j] - mean) * rstd * g[j] + b[j]);
      lds[tl * 32 + (((dl >> 1)    ) ^ k)] = (unsigned)h[0] | ((unsigned)h[1] << 16);
      lds[tl * 32 + (((dl >> 1) + 1) ^ k)] = (unsigned)h[2] | ((unsigned)h[3] << 16);
    }
  }
  __syncthreads();
  {
    int dl = tid >> 2;          // local d 0..63
    int tc = (tid & 3) * 16;    // t chunk base (16 consecutive t)
    short8v o0, o1;
#pragma unroll
    for (int i = 0; i < 16; ++i) {
      int t = tc + i;
      unsigned w = lds[t * 32 + ((dl >> 1) ^ (t & 31))];
      unsigned short val = (dl & 1) ? (unsigned short)(w >> 16)
                                    : (unsigned short)(w & 0xffffu);
      if (i < 8) o0[i] = (short)val; else o1[i - 8] = (short)val;
    }
    int d  = d0 + dl;
    int np = d >> 7, r = d & 127;
    int tb  = t0 + tc;
    int ks  = tb >> 5;
    int kq0 = (tb >> 3) & 3;     // 0 or 2
    size_t img = ((size_t)(bb * 16 + np) * 16 + ks) * 4096;  // ushort units
    *reinterpret_cast<short8v*>(Bimg + img + (size_t)swz(r, kq0)     * 8) = o0;
    *reinterpret_cast<short8v*>(Bimg + img + (size_t)swz(r, kq0 + 1) * 8) = o1;
  }
}

// ---------------- K4: out = gelu(W_e @ y + bias_e) + x ----------------
// BM=128 BN=128 BK=32, 4 waves (2x2), each wave 64x64 = 4x4 mfma_f32_16x16x32_bf16
__global__ __launch_bounds__(256) void k_gemm(const unsigned short* __restrict__ Aimg,
                                              const unsigned short* __restrict__ Bimg,
                                              const float* __restrict__ bias,
                                              const float* __restrict__ x,
                                              float* __restrict__ out) {
  int np = blockIdx.x, mp = blockIdx.y, bb = blockIdx.z;
  int e = bb < 3 ? bb : 3;
  const char* Abase = (const char*)(Aimg + ((size_t)(e  * 4 + mp) * 16) * 4096);
  const char* Bbase = (const char*)(Bimg + ((size_t)(bb * 16 + np) * 16) * 4096);
  __shared__ unsigned short Al[4096];
  __shared__ unsigned short Bl[4096];
  int tid = threadIdx.x;
  int lane = tid & 63, wid = tid >> 6;
  int wr = wid >> 1, wc = wid & 1;
  int lr = lane & 15, kq = lane >> 4;

  int aoff[4], boff[4];
#pragma unroll
  for (int mi = 0; mi < 4; ++mi) { int rr = wr * 64 + mi * 16 + lr; aoff[mi] = swz(rr, kq) * 8; }
#pragma unroll
  for (int ni = 0; ni < 4; ++ni) { int rr = wc * 64 + ni * 16 + lr; boff[ni] = swz(rr, kq) * 8; }

  accv acc[4][4] = {};

  for (int ks = 0; ks < 16; ++ks) {
#pragma unroll
    for (int i = 0; i < 2; ++i) {
      GLL16(Abase + ks * 8192 + i * 4096 + tid * 16, (char*)Al + i * 4096 + wid * 1024);
      GLL16(Bbase + ks * 8192 + i * 4096 + tid * 16, (char*)Bl + i * 4096 + wid * 1024);
    }
    __syncthreads();
    short8v a[4], b[4];
#pragma unroll
    for (int mi = 0; mi < 4; ++mi) a[mi] = *reinterpret_cast<const short8v*>(&Al[aoff[mi]]);
#pragma unroll
    for (int ni = 0; ni < 4; ++ni) b[ni] = *reinterpret_cast<const short8v*>(&Bl[boff[ni]]);
#pragma unroll
    for (int mi = 0; mi < 4; ++mi)
#pragma unroll
      for (int ni = 0; ni < 4; ++ni)
        acc[mi][ni] = __builtin_amdgcn_mfma_f32_16x16x32_bf16(a[mi], b[ni], acc[mi][ni], 0, 0, 0);
    __syncthreads();
  }

  // epilogue: gelu(acc + bias_e[s]) + x   (tanh/sigmoid-form gelu)
  const float* bp = bias + (size_t)e * NS;
  int m0 = mp * 128, n0 = np * 128;
#pragma unroll
  for (int mi = 0; mi < 4; ++mi) {
#pragma unroll
    for (int ni = 0; ni < 4; ++ni) {
#pragma unroll
      for (int r = 0; r < 4; ++r) {
        int s = m0 + wr * 64 + mi * 16 + ((lane >> 4) * 4) + r;
        int d = n0 + wc * 64 + ni * 16 + (lane & 15);
        float v = acc[mi][ni][r] + bp[s];
        float u = 1.5957691216f * (v + 0.044715f * v * v * v);
        float g = v / (1.0f + __expf(-u));
        size_t idx = ((size_t)bb * NS + s) * ND + d;
        out[idx] = g + x[idx];
      }
    }
  }
}

extern "C" void kernel_launch(void* const* d_in, const int* in_sizes, int n_in,
                              void* d_out, int out_size, void* d_ws, size_t ws_size,
                              hipStream_t stream) {
  const float* x     = (const float*)d_in[0];
  const float* gamma = (const float*)d_in[1];
  const float* beta  = (const float*)d_in[2];
  // d_in[3] = Wc, d_in[4] = bc : router is dead code in the reference (unused output)
  const float* W     = (const float*)d_in[5];
  const float* bias  = (const float*)d_in[6];
  float* out = (float*)d_out;

  // ws layout: Aimg 2MB | mv 64KB | Bimg 32MB
  unsigned short* Aimg = (unsigned short*)d_ws;
  float*          mv   = (float*)((char*)d_ws + (2ull << 20));
  unsigned short* Bimg = (unsigned short*)((char*)d_ws + (2ull << 20) + (64ull << 10));

  k_meanvar<<<NB * NS / 4, 256, 0, stream>>>(x, mv);
  k_wcvt<<<dim3(16, 4, 4), 256, 0, stream>>>(W, Aimg);
  k_normT<<<dim3(ND / 64, NS / 64, NB), 256, 0, stream>>>(x, mv, gamma, beta, Bimg);
  k_gemm<<<dim3(ND / 128, NS / 128, NB), 256, 0, stream>>>(Aimg, Bimg, bias, x, out);
}